// Round 3
// baseline (52618.585 us; speedup 1.0000x reference)
//
#include <hip/hip_runtime.h>
#include <hip/hip_bf16.h>

// LSTM: B=64, S=512, H=768, L=2. Persistent scan per layer (plain launch,
// residency by resource arithmetic: 256 WGs x 1 WG/CU on 256 CUs),
// split-bf16 (hi+lo) precision: weights in registers (hi+lo), fused input
// projection (K=1536), per-step global-flag barrier. 3 MFMAs per 32-K chunk.

#define HID 768
#define FH  3072
#define SEQ 512
#define BAT 64
#define NGROUP 4
#define GB  16           // batches per group
#define WPG 64           // workgroups per group
#define CPW 12           // h-columns per workgroup
#define NWG (NGROUP*WPG) // 256
#define TPB 192          // 3 waves

typedef __attribute__((ext_vector_type(8))) __bf16 bf16x8;
typedef __attribute__((ext_vector_type(4))) float f32x4;

__device__ __forceinline__ float sigm(float z) {
  return 1.f / (1.f + __expf(-z));
}
__device__ __forceinline__ float tanh_fast(float x) {
  float a = fabsf(x);
  float e = __expf(-2.f * a);
  float t = (1.f - e) / (1.f + e);
  return copysignf(t, x);
}
// Split 8 contiguous floats into hi/lo bf16 pairs (RNE): x = hi + lo + O(2^-18 x)
__device__ __forceinline__ void split8(const float* p, bf16x8& hi, bf16x8& lo) {
  const float4* q = (const float4*)p;
  float4 a = q[0], b = q[1];
  float v[8] = {a.x, a.y, a.z, a.w, b.x, b.y, b.z, b.w};
#pragma unroll
  for (int i = 0; i < 8; ++i) {
    __bf16 h = (__bf16)v[i];
    hi[i] = h;
    lo[i] = (__bf16)(v[i] - (float)h);
  }
}

// x [64][512][768] fp32 -> xhi/xlo [512][64][768] bf16 (seq-major)
__global__ void split_x(const float* __restrict__ x,
                        __bf16* __restrict__ xhi, __bf16* __restrict__ xlo) {
  const int nchunk = BAT * SEQ * (HID / 8);
  for (int c = blockIdx.x * blockDim.x + threadIdx.x; c < nchunk;
       c += gridDim.x * blockDim.x) {
    int h0 = (c % (HID / 8)) * 8;
    int bs = c / (HID / 8);          // b*SEQ + s
    int b = bs / SEQ, s = bs % SEQ;
    bf16x8 hi, lo;
    split8(x + (size_t)bs * HID + h0, hi, lo);
    size_t o = ((size_t)s * BAT + b) * HID + h0;
    *(bf16x8*)(xhi + o) = hi;
    *(bf16x8*)(xlo + o) = lo;
  }
}

template<int LAYER>
__global__ void __launch_bounds__(TPB, 1)
lstm_scan(const __bf16* __restrict__ xs_hi,  // input pairs [512][64][768] seq-major
          const __bf16* __restrict__ xs_lo,
          const float* __restrict__ mask,    // [64][512]
          const float* __restrict__ Wih,     // [3072][768] this layer
          const float* __restrict__ Whh,     // [3072][768] this layer
          const float* __restrict__ bih,
          const float* __restrict__ bhh,
          __bf16* __restrict__ hb_hi,        // h publish/read pairs:
          __bf16* __restrict__ hb_lo,        //  L0: [512][64][768] (= L1 input), L1: [2][64][768]
          float* __restrict__ out_f,         // L1 dest [64][512][768]
          float* __restrict__ hn,            // [64][768] this layer
          float* __restrict__ cn,            // [64][768] this layer
          int* __restrict__ flags)           // [NWG] this layer, zeroed
{
  const int wg  = blockIdx.x;
  const int grp = wg >> 6;         // 0..3
  const int wid = wg & 63;         // 0..63
  const int tid = threadIdx.x;
  const int wv  = tid >> 6;        // wave 0..2
  const int l   = tid & 63;
  const int l15 = l & 15;
  const int lhi = l >> 4;

  // ---- A fragments (weights, hi+lo) -> registers. M-row m = 4*c_loc + gate.
  // A-operand lane map: row = l&15, k = kk*32 + (l>>4)*8 + i
  const int mA   = l15;
  const int colA = wid*CPW + wv*4 + (mA >> 2);
  const int qA   = mA & 3;
  const float* wih_row = Wih + (size_t)(qA*HID + colA)*HID + lhi*8;
  const float* whh_row = Whh + (size_t)(qA*HID + colA)*HID + lhi*8;
  bf16x8 ah[48], al[48];
#pragma unroll
  for (int kk = 0; kk < 24; ++kk) split8(wih_row + kk*32, ah[kk],    al[kk]);
#pragma unroll
  for (int kk = 0; kk < 24; ++kk) split8(whh_row + kk*32, ah[24+kk], al[24+kk]);

  // ---- per-lane output ownership (D: col = l&15 -> batch, row = (l>>4)*4+r -> gate r)
  const int batch = grp*GB + l15;
  const int col   = wid*CPW + wv*4 + lhi;
  float bias[4];
#pragma unroll
  for (int r = 0; r < 4; ++r) bias[r] = bih[r*HID + col] + bhh[r*HID + col];
  const float* mrow = mask + batch*SEQ;
  int* gflags = flags + grp*WPG;

  float cstate = 0.f;

#pragma unroll 1
  for (int s = 0; s < SEQ; ++s) {
    f32x4 acc[4];
#pragma unroll
    for (int r = 0; r < 4; ++r) acc[r] = f32x4{0.f, 0.f, 0.f, 0.f};

    // ---- input contribution (independent of peers) ----
    {
      const __bf16* xh = xs_hi + ((size_t)s*BAT + batch)*HID + lhi*8;
      const __bf16* xl = xs_lo + ((size_t)s*BAT + batch)*HID + lhi*8;
#pragma unroll
      for (int kk = 0; kk < 24; ++kk) {
        bf16x8 bhi = *(const bf16x8*)(xh + kk*32);
        bf16x8 blo = *(const bf16x8*)(xl + kk*32);
        acc[(3*kk+0)&3] = __builtin_amdgcn_mfma_f32_16x16x32_bf16(ah[kk], bhi, acc[(3*kk+0)&3], 0, 0, 0);
        acc[(3*kk+1)&3] = __builtin_amdgcn_mfma_f32_16x16x32_bf16(al[kk], bhi, acc[(3*kk+1)&3], 0, 0, 0);
        acc[(3*kk+2)&3] = __builtin_amdgcn_mfma_f32_16x16x32_bf16(ah[kk], blo, acc[(3*kk+2)&3], 0, 0, 0);
      }
    }

    // ---- recurrent contribution ----
    if (s > 0) {
      if (tid < 64) {
        while (true) {
          int v = __hip_atomic_load(gflags + l, __ATOMIC_RELAXED, __HIP_MEMORY_SCOPE_AGENT);
          if (__all(v >= s)) break;
          __builtin_amdgcn_s_sleep(1);
        }
      }
      __syncthreads();
      __threadfence();   // acquire: invalidate stale caches before reading peers' h
      size_t rd_row = (LAYER == 0) ? ((size_t)(s-1)*BAT + batch)
                                   : ((size_t)((s-1) & 1)*BAT + batch);
      const __bf16* hh = hb_hi + rd_row*HID + lhi*8;
      const __bf16* hl = hb_lo + rd_row*HID + lhi*8;
#pragma unroll
      for (int kk = 0; kk < 24; ++kk) {
        bf16x8 bhi = *(const bf16x8*)(hh + kk*32);
        bf16x8 blo = *(const bf16x8*)(hl + kk*32);
        acc[(3*kk+0)&3] = __builtin_amdgcn_mfma_f32_16x16x32_bf16(ah[24+kk], bhi, acc[(3*kk+0)&3], 0, 0, 0);
        acc[(3*kk+1)&3] = __builtin_amdgcn_mfma_f32_16x16x32_bf16(al[24+kk], bhi, acc[(3*kk+1)&3], 0, 0, 0);
        acc[(3*kk+2)&3] = __builtin_amdgcn_mfma_f32_16x16x32_bf16(ah[24+kk], blo, acc[(3*kk+2)&3], 0, 0, 0);
      }
    }

    // ---- gates / state update ----
    float zi = acc[0][0]+acc[1][0]+acc[2][0]+acc[3][0] + bias[0];
    float zf = acc[0][1]+acc[1][1]+acc[2][1]+acc[3][1] + bias[1];
    float zg = acc[0][2]+acc[1][2]+acc[2][2]+acc[3][2] + bias[2];
    float zo = acc[0][3]+acc[1][3]+acc[2][3]+acc[3][3] + bias[3];
    float iv = sigm(zi), fv = sigm(zf), gv = tanh_fast(zg), ov = sigm(zo);
    float c  = fv*cstate + iv*gv;
    float hv = ov * tanh_fast(c);
    float m  = mrow[s];
    hv *= m; c *= m; cstate = c;

    // ---- publish h_s as hi/lo pair ----
    __bf16 hvh = (__bf16)hv;
    __bf16 hvl = (__bf16)(hv - (float)hvh);
    size_t wr_row = (LAYER == 0) ? ((size_t)s*BAT + batch)
                                 : ((size_t)(s & 1)*BAT + batch);
    hb_hi[wr_row*HID + col] = hvh;
    hb_lo[wr_row*HID + col] = hvl;
    if constexpr (LAYER == 1) {
      __builtin_nontemporal_store(hv, out_f + (size_t)(batch*SEQ + s)*HID + col);
    }
    if (s == SEQ - 1) {
      hn[batch*HID + col] = hv;
      cn[batch*HID + col] = c;
    }

    __threadfence();       // release: drain stores (incl. L2 writeback)
    __syncthreads();       // all waves' fences done
    if (tid == 0)
      __hip_atomic_store(gflags + wid, s + 1, __ATOMIC_RELEASE, __HIP_MEMORY_SCOPE_AGENT);
  }
}

extern "C" void kernel_launch(void* const* d_in, const int* in_sizes, int n_in,
                              void* d_out, int out_size, void* d_ws, size_t ws_size,
                              hipStream_t stream) {
  const float* x    = (const float*)d_in[0];
  const float* mask = (const float*)d_in[1];
  const float* Wih  = (const float*)d_in[2];
  const float* Whh  = (const float*)d_in[3];
  const float* bih  = (const float*)d_in[4];
  const float* bhh  = (const float*)d_in[5];
  float* out = (float*)d_out;

  char* ws = (char*)d_ws;
  const size_t PAIR = (size_t)SEQ * BAT * HID * sizeof(__bf16);  // 50331648
  __bf16* xhi = (__bf16*)(ws);
  __bf16* xlo = (__bf16*)(ws + PAIR);
  __bf16* ohi = (__bf16*)(ws + 2*PAIR);
  __bf16* olo = (__bf16*)(ws + 3*PAIR);
  __bf16* hhi = (__bf16*)(ws + 4*PAIR);                    // 2*64*768*2 = 196608
  __bf16* hlo = (__bf16*)(ws + 4*PAIR + 196608);
  int*    flags = (int*)(ws + 4*PAIR + 2*196608);          // 2*NWG*4

  hipMemsetAsync(flags, 0, 2*NWG*sizeof(int), stream);
  split_x<<<2048, 256, 0, stream>>>(x, xhi, xlo);

  float* hn = out + 25165824;            // [2][64][768]
  float* cn = out + 25165824 + 98304;    // [2][64][768]

  // ---- layer 0 ----
  lstm_scan<0><<<dim3(NWG), dim3(TPB), 0, stream>>>(
      xhi, xlo, mask, Wih, Whh, bih, bhh,
      ohi, olo, /*out_f=*/nullptr, hn, cn, flags);

  // ---- layer 1 ----
  lstm_scan<1><<<dim3(NWG), dim3(TPB), 0, stream>>>(
      ohi, olo, mask,
      Wih + (size_t)FH*HID, Whh + (size_t)FH*HID, bih + FH, bhh + FH,
      hhi, hlo, /*out_f=*/out, hn + 49152, cn + 49152, flags + NWG);
}

// Round 4
// 20894.527 us; speedup vs baseline: 2.5183x; 2.5183x over previous
//
#include <hip/hip_runtime.h>
#include <hip/hip_bf16.h>

// LSTM: B=64, S=512, H=768, L=2. Persistent scan per layer, weights in
// registers, split-bf16 (hi+lo) numerics, fused input projection.
// Cross-WG h exchange via RELAXED AGENT atomics (cache-bypass, MALL-coherent)
// -- NO fences, no L2 writeback/invalidate on the per-step critical path.

#define HID 768
#define FH  3072
#define SEQ 512
#define BAT 64
#define GB  16           // batches per group
#define WPG 64           // workgroups per group
#define CPW 12           // h-columns per workgroup
#define NWG 256
#define TPB 192          // 3 waves

typedef __attribute__((ext_vector_type(8))) __bf16 bf16x8;
typedef __attribute__((ext_vector_type(4))) float f32x4;
typedef unsigned int u32;
typedef unsigned long long u64;

__device__ __forceinline__ float sigm(float z) {
  return 1.f / (1.f + __expf(-z));
}
__device__ __forceinline__ float tanh_fast(float x) {
  float a = fabsf(x);
  float e = __expf(-2.f * a);
  float t = (1.f - e) / (1.f + e);
  return copysignf(t, x);
}
__device__ __forceinline__ unsigned short bfbits(__bf16 b) {
  union { __bf16 b; unsigned short s; } u; u.b = b; return u.s;
}
__device__ __forceinline__ __bf16 bits2bf(unsigned short s) {
  union { unsigned short s; __bf16 b; } u; u.s = s; return u.b;
}
// Split 8 floats into hi/lo bf16 (RNE): x = hi + lo + O(2^-18 x)
__device__ __forceinline__ void split8(const float* p, bf16x8& hi, bf16x8& lo) {
  const float4* q = (const float4*)p;
  float4 a = q[0], b = q[1];
  float v[8] = {a.x, a.y, a.z, a.w, b.x, b.y, b.z, b.w};
#pragma unroll
  for (int i = 0; i < 8; ++i) {
    __bf16 h = (__bf16)v[i];
    hi[i] = h;
    lo[i] = (__bf16)(v[i] - (float)h);
  }
}
__device__ __forceinline__ void unpack8(const u32 w[8], bf16x8& hi, bf16x8& lo) {
#pragma unroll
  for (int i = 0; i < 8; ++i) {
    hi[i] = bits2bf((unsigned short)(w[i] >> 16));
    lo[i] = bits2bf((unsigned short)(w[i] & 0xffffu));
  }
}

// x [64][512][768] fp32 -> xhi/xlo [512][64][768] bf16 (seq-major)
__global__ void pack_x(const float* __restrict__ x,
                       __bf16* __restrict__ xhi, __bf16* __restrict__ xlo) {
  const int nchunk = BAT * SEQ * (HID / 8);
  for (int c = blockIdx.x * blockDim.x + threadIdx.x; c < nchunk;
       c += gridDim.x * blockDim.x) {
    int h0 = (c % (HID / 8)) * 8;
    int bs = c / (HID / 8);          // b*SEQ + s
    int b = bs / SEQ, s = bs % SEQ;
    bf16x8 hi, lo;
    split8(x + (size_t)bs * HID + h0, hi, lo);
    size_t o = ((size_t)s * BAT + b) * HID + h0;
    *(bf16x8*)(xhi + o) = hi;
    *(bf16x8*)(xlo + o) = lo;
  }
}

template<int LAYER>
__global__ void __launch_bounds__(TPB, 1)
lstm_scan(const __bf16* __restrict__ xs_hi,  // L0 input [512][64][768]
          const __bf16* __restrict__ xs_lo,
          const u32* __restrict__ xs_pk,     // L1 input: packed hi|lo u32 [512][64][768]
          const float* __restrict__ mask,    // [64][512]
          const float* __restrict__ Wih,     // [3072][768] this layer
          const float* __restrict__ Whh,
          const float* __restrict__ bih,
          const float* __restrict__ bhh,
          u32* __restrict__ hex,             // h exchange (packed u32):
                                             //  L0: [512][64][768] (= L1 input), L1: [2][64][768]
          float* __restrict__ out_f,         // L1 dest [64][512][768]
          float* __restrict__ hn,            // [64][768] this layer
          float* __restrict__ cn,
          int* __restrict__ flags)           // [NWG] this layer, zeroed
{
  const int wg  = blockIdx.x;
  const int grp = wg >> 6;         // 0..3
  const int wid = wg & 63;         // 0..63
  const int tid = threadIdx.x;
  const int wv  = tid >> 6;        // wave 0..2
  const int l   = tid & 63;
  const int l15 = l & 15;
  const int lhi = l >> 4;

  // ---- A fragments (weights, hi+lo) -> registers. M-row m = 4*c_loc + gate.
  // A-operand lane map: row = l&15, k = kk*32 + (l>>4)*8 + i
  const int mA   = l15;
  const int colA = wid*CPW + wv*4 + (mA >> 2);
  const int qA   = mA & 3;
  const float* wih_row = Wih + (size_t)(qA*HID + colA)*HID + lhi*8;
  const float* whh_row = Whh + (size_t)(qA*HID + colA)*HID + lhi*8;
  bf16x8 ah[48], al[48];
#pragma unroll
  for (int kk = 0; kk < 24; ++kk) split8(wih_row + kk*32, ah[kk],    al[kk]);
#pragma unroll
  for (int kk = 0; kk < 24; ++kk) split8(whh_row + kk*32, ah[24+kk], al[24+kk]);

  // ---- per-lane output ownership (D: col = l&15 -> batch, row = (l>>4)*4+r -> gate r)
  const int batch = grp*GB + l15;
  const int col   = wid*CPW + wv*4 + lhi;
  float bias[4];
#pragma unroll
  for (int r = 0; r < 4; ++r) bias[r] = bih[r*HID + col] + bhh[r*HID + col];
  const float* mrow = mask + batch*SEQ;
  int* gflags = flags + grp*WPG;

  float cstate = 0.f;

#pragma unroll 1
  for (int s = 0; s < SEQ; ++s) {
    f32x4 acc[4];
#pragma unroll
    for (int r = 0; r < 4; ++r) acc[r] = f32x4{0.f, 0.f, 0.f, 0.f};

    // ---- input contribution (independent of peers) ----
    if constexpr (LAYER == 0) {
      const __bf16* xh = xs_hi + ((size_t)s*BAT + batch)*HID + lhi*8;
      const __bf16* xl = xs_lo + ((size_t)s*BAT + batch)*HID + lhi*8;
#pragma unroll
      for (int kk = 0; kk < 24; ++kk) {
        bf16x8 bhi = *(const bf16x8*)(xh + kk*32);
        bf16x8 blo = *(const bf16x8*)(xl + kk*32);
        acc[(3*kk+0)&3] = __builtin_amdgcn_mfma_f32_16x16x32_bf16(ah[kk], bhi, acc[(3*kk+0)&3], 0, 0, 0);
        acc[(3*kk+1)&3] = __builtin_amdgcn_mfma_f32_16x16x32_bf16(al[kk], bhi, acc[(3*kk+1)&3], 0, 0, 0);
        acc[(3*kk+2)&3] = __builtin_amdgcn_mfma_f32_16x16x32_bf16(ah[kk], blo, acc[(3*kk+2)&3], 0, 0, 0);
      }
    } else {
      const u32* xrow = xs_pk + ((size_t)s*BAT + batch)*HID + lhi*8;
#pragma unroll
      for (int kk = 0; kk < 24; ++kk) {
        const uint4* p = (const uint4*)(xrow + kk*32);
        uint4 a = p[0], b = p[1];
        u32 w[8] = {a.x, a.y, a.z, a.w, b.x, b.y, b.z, b.w};
        bf16x8 bhi, blo;
        unpack8(w, bhi, blo);
        acc[(3*kk+0)&3] = __builtin_amdgcn_mfma_f32_16x16x32_bf16(ah[kk], bhi, acc[(3*kk+0)&3], 0, 0, 0);
        acc[(3*kk+1)&3] = __builtin_amdgcn_mfma_f32_16x16x32_bf16(al[kk], bhi, acc[(3*kk+1)&3], 0, 0, 0);
        acc[(3*kk+2)&3] = __builtin_amdgcn_mfma_f32_16x16x32_bf16(ah[kk], blo, acc[(3*kk+2)&3], 0, 0, 0);
      }
    }

    // ---- recurrent contribution ----
    if (s > 0) {
      if (tid < 64) {
        while (true) {
          int v = __hip_atomic_load(gflags + l, __ATOMIC_RELAXED, __HIP_MEMORY_SCOPE_AGENT);
          if (__all(v >= s)) break;
          __builtin_amdgcn_s_sleep(1);
        }
      }
      __syncthreads();   // poll done; also a compiler barrier (no fence emitted)
      size_t rd_row = (LAYER == 0) ? ((size_t)(s-1)*BAT + batch)
                                   : ((size_t)((s-1) & 1)*BAT + batch);
      const u32* hrow = hex + rd_row*HID + lhi*8;
#pragma unroll
      for (int kk = 0; kk < 24; ++kk) {
        const u64* p = (const u64*)(hrow + kk*32);
        u64 q0 = __hip_atomic_load(p+0, __ATOMIC_RELAXED, __HIP_MEMORY_SCOPE_AGENT);
        u64 q1 = __hip_atomic_load(p+1, __ATOMIC_RELAXED, __HIP_MEMORY_SCOPE_AGENT);
        u64 q2 = __hip_atomic_load(p+2, __ATOMIC_RELAXED, __HIP_MEMORY_SCOPE_AGENT);
        u64 q3 = __hip_atomic_load(p+3, __ATOMIC_RELAXED, __HIP_MEMORY_SCOPE_AGENT);
        u32 w[8] = {(u32)q0, (u32)(q0 >> 32), (u32)q1, (u32)(q1 >> 32),
                    (u32)q2, (u32)(q2 >> 32), (u32)q3, (u32)(q3 >> 32)};
        bf16x8 bhi, blo;
        unpack8(w, bhi, blo);
        acc[(3*kk+0)&3] = __builtin_amdgcn_mfma_f32_16x16x32_bf16(ah[24+kk], bhi, acc[(3*kk+0)&3], 0, 0, 0);
        acc[(3*kk+1)&3] = __builtin_amdgcn_mfma_f32_16x16x32_bf16(al[24+kk], bhi, acc[(3*kk+1)&3], 0, 0, 0);
        acc[(3*kk+2)&3] = __builtin_amdgcn_mfma_f32_16x16x32_bf16(ah[24+kk], blo, acc[(3*kk+2)&3], 0, 0, 0);
      }
    }

    // ---- gates / state update ----
    float zi = acc[0][0]+acc[1][0]+acc[2][0]+acc[3][0] + bias[0];
    float zf = acc[0][1]+acc[1][1]+acc[2][1]+acc[3][1] + bias[1];
    float zg = acc[0][2]+acc[1][2]+acc[2][2]+acc[3][2] + bias[2];
    float zo = acc[0][3]+acc[1][3]+acc[2][3]+acc[3][3] + bias[3];
    float iv = sigm(zi), fv = sigm(zf), gv = tanh_fast(zg), ov = sigm(zo);
    float c  = fv*cstate + iv*gv;
    float hv = ov * tanh_fast(c);
    float m  = mrow[s];
    hv *= m; c *= m; cstate = c;

    // ---- publish h_s as packed hi|lo u32 (device-coherent store) ----
    __bf16 hvh = (__bf16)hv;
    __bf16 hvl = (__bf16)(hv - (float)hvh);
    u32 hw = ((u32)bfbits(hvh) << 16) | (u32)bfbits(hvl);
    size_t wr_row = (LAYER == 0) ? ((size_t)s*BAT + batch)
                                 : ((size_t)(s & 1)*BAT + batch);
    __hip_atomic_store(hex + wr_row*HID + col, hw,
                       __ATOMIC_RELAXED, __HIP_MEMORY_SCOPE_AGENT);
    if constexpr (LAYER == 1) {
      __builtin_nontemporal_store(hv, out_f + (size_t)(batch*SEQ + s)*HID + col);
    }
    if (s == SEQ - 1) {
      hn[batch*HID + col] = hv;
      cn[batch*HID + col] = c;
    }

    // ---- ordering: store-ack (agent visibility) then flag ----
    asm volatile("s_waitcnt vmcnt(0)" ::: "memory");
    __syncthreads();     // every wave has drained its stores
    if (tid == 0)
      __hip_atomic_store(gflags + wid, s + 1,
                         __ATOMIC_RELAXED, __HIP_MEMORY_SCOPE_AGENT);
  }
}

extern "C" void kernel_launch(void* const* d_in, const int* in_sizes, int n_in,
                              void* d_out, int out_size, void* d_ws, size_t ws_size,
                              hipStream_t stream) {
  const float* x    = (const float*)d_in[0];
  const float* mask = (const float*)d_in[1];
  const float* Wih  = (const float*)d_in[2];
  const float* Whh  = (const float*)d_in[3];
  const float* bih  = (const float*)d_in[4];
  const float* bhh  = (const float*)d_in[5];
  float* out = (float*)d_out;

  char* ws = (char*)d_ws;
  const size_t PAIR = (size_t)SEQ * BAT * HID * sizeof(__bf16);  // 50331648
  __bf16* xhi = (__bf16*)(ws);
  __bf16* xlo = (__bf16*)(ws + PAIR);
  u32*    opk = (u32*)(ws + 2*PAIR);                 // [512][64][768] u32 = 100663296 B
  u32*    hpk = (u32*)(ws + 4*PAIR);                 // [2][64][768] u32 = 393216 B
  int*    flags = (int*)(ws + 4*PAIR + 393216);      // 2*NWG*4

  hipMemsetAsync(flags, 0, 2*NWG*sizeof(int), stream);
  pack_x<<<2048, 256, 0, stream>>>(x, xhi, xlo);

  float* hn = out + 25165824;            // [2][64][768]
  float* cn = out + 25165824 + 98304;

  // ---- layer 0 ----
  lstm_scan<0><<<dim3(NWG), dim3(TPB), 0, stream>>>(
      xhi, xlo, /*xs_pk=*/nullptr, mask, Wih, Whh, bih, bhh,
      /*hex=*/opk, /*out_f=*/nullptr, hn, cn, flags);

  // ---- layer 1 ----
  lstm_scan<1><<<dim3(NWG), dim3(TPB), 0, stream>>>(
      /*xs_hi=*/nullptr, /*xs_lo=*/nullptr, /*xs_pk=*/opk, mask,
      Wih + (size_t)FH*HID, Whh + (size_t)FH*HID, bih + FH, bhh + FH,
      /*hex=*/hpk, /*out_f=*/out, hn + 49152, cn + 49152, flags + NWG);
}

// Round 5
// 19141.002 us; speedup vs baseline: 2.7490x; 1.0916x over previous
//
#include <hip/hip_runtime.h>
#include <hip/hip_bf16.h>

// LSTM: B=64, S=512, H=768, L=2. Persistent scan per layer, weights in
// registers (split-bf16 hi+lo), fused input projection (K=1536).
// h exchange: producer MALL-bypass stores (relaxed agent atomics) + vmcnt ack
// + flag; consumers use PLAIN CACHED loads on write-once streaming buffers
// (fresh addresses each step -> no stale-line hazard, L1/L2 de-duplicate).

#define HID 768
#define FH  3072
#define SEQ 512
#define BAT 64
#define GB  16           // batches per group
#define WPG 64           // workgroups per group
#define CPW 12           // h-columns per workgroup
#define NWG 256
#define TPB 192          // 3 waves

typedef __attribute__((ext_vector_type(8))) __bf16 bf16x8;
typedef __attribute__((ext_vector_type(4))) float f32x4;
typedef unsigned int u32;

__device__ __forceinline__ float sigm(float z) {
  return 1.f / (1.f + __expf(-z));
}
__device__ __forceinline__ float tanh_fast(float x) {
  float a = fabsf(x);
  float e = __expf(-2.f * a);
  float t = (1.f - e) / (1.f + e);
  return copysignf(t, x);
}
__device__ __forceinline__ unsigned short bfbits(__bf16 b) {
  union { __bf16 b; unsigned short s; } u; u.b = b; return u.s;
}
__device__ __forceinline__ __bf16 bits2bf(unsigned short s) {
  union { unsigned short s; __bf16 b; } u; u.s = s; return u.b;
}
// Split float -> hi/lo bf16 (RNE), packed as (hi<<16)|lo
__device__ __forceinline__ u32 packsplit(float v) {
  __bf16 h = (__bf16)v;
  __bf16 l = (__bf16)(v - (float)h);
  return ((u32)bfbits(h) << 16) | (u32)bfbits(l);
}
__device__ __forceinline__ void split8(const float* p, bf16x8& hi, bf16x8& lo) {
  const float4* q = (const float4*)p;
  float4 a = q[0], b = q[1];
  float v[8] = {a.x, a.y, a.z, a.w, b.x, b.y, b.z, b.w};
#pragma unroll
  for (int i = 0; i < 8; ++i) {
    __bf16 h = (__bf16)v[i];
    hi[i] = h;
    lo[i] = (__bf16)(v[i] - (float)h);
  }
}
__device__ __forceinline__ void unpack8(const u32 w[8], bf16x8& hi, bf16x8& lo) {
#pragma unroll
  for (int i = 0; i < 8; ++i) {
    hi[i] = bits2bf((unsigned short)(w[i] >> 16));
    lo[i] = bits2bf((unsigned short)(w[i] & 0xffffu));
  }
}

// x [64][512][768] fp32 -> xpk [512][64][768] packed hi|lo u32 (seq-major)
__global__ void pack_x(const float* __restrict__ x, u32* __restrict__ xpk) {
  const int nchunk = BAT * SEQ * (HID / 8);
  for (int c = blockIdx.x * blockDim.x + threadIdx.x; c < nchunk;
       c += gridDim.x * blockDim.x) {
    int h0 = (c % (HID / 8)) * 8;
    int bs = c / (HID / 8);          // b*SEQ + s
    int b = bs / SEQ, s = bs % SEQ;
    const float4* q = (const float4*)(x + (size_t)bs * HID + h0);
    float4 a = q[0], bb = q[1];
    u32 w[8] = {packsplit(a.x),  packsplit(a.y),  packsplit(a.z),  packsplit(a.w),
                packsplit(bb.x), packsplit(bb.y), packsplit(bb.z), packsplit(bb.w)};
    size_t o = ((size_t)s * BAT + b) * HID + h0;
    *(uint4*)(xpk + o)     = make_uint4(w[0], w[1], w[2], w[3]);
    *(uint4*)(xpk + o + 4) = make_uint4(w[4], w[5], w[6], w[7]);
  }
}

template<int WRITE_OUT>
__global__ void __launch_bounds__(TPB, 1)
lstm_scan(const u32* __restrict__ xs_pk,    // input stream [512][64][768] packed
          const float* __restrict__ mask,   // [64][512]
          const float* __restrict__ Wih,    // [3072][768] this layer
          const float* __restrict__ Whh,
          const float* __restrict__ bih,
          const float* __restrict__ bhh,
          u32* __restrict__ hout,           // h stream [512][64][768] packed
          float* __restrict__ out_f,        // WRITE_OUT: [64][512][768]
          float* __restrict__ hn,           // [64][768] this layer
          float* __restrict__ cn,
          int* __restrict__ flags)          // [NWG] this layer, zeroed
{
  const int wg  = blockIdx.x;
  const int grp = wg >> 6;         // 0..3
  const int wid = wg & 63;         // 0..63
  const int tid = threadIdx.x;
  const int wv  = tid >> 6;        // wave 0..2
  const int l   = tid & 63;
  const int l15 = l & 15;
  const int lhi = l >> 4;

  // ---- A fragments (weights, hi+lo) -> registers. M-row m = 4*c_loc + gate.
  // A-operand lane map: row = l&15, k = kk*32 + (l>>4)*8 + i
  const int mA   = l15;
  const int colA = wid*CPW + wv*4 + (mA >> 2);
  const int qA   = mA & 3;
  const float* wih_row = Wih + (size_t)(qA*HID + colA)*HID + lhi*8;
  const float* whh_row = Whh + (size_t)(qA*HID + colA)*HID + lhi*8;
  bf16x8 ah[48], al[48];
#pragma unroll
  for (int kk = 0; kk < 24; ++kk) split8(wih_row + kk*32, ah[kk],    al[kk]);
#pragma unroll
  for (int kk = 0; kk < 24; ++kk) split8(whh_row + kk*32, ah[24+kk], al[24+kk]);

  // ---- per-lane output ownership (D: col = l&15 -> batch, row = (l>>4)*4+r -> gate r)
  const int batch = grp*GB + l15;
  const int col   = wid*CPW + wv*4 + lhi;
  float bias[4];
#pragma unroll
  for (int r = 0; r < 4; ++r) bias[r] = bih[r*HID + col] + bhh[r*HID + col];
  const float* mrow = mask + batch*SEQ;
  int* gflags = flags + grp*WPG;

  float cstate = 0.f;

#pragma unroll 1
  for (int s = 0; s < SEQ; ++s) {
    f32x4 acc[4];
#pragma unroll
    for (int r = 0; r < 4; ++r) acc[r] = f32x4{0.f, 0.f, 0.f, 0.f};

    // ---- input contribution (plain cached loads; fresh addresses per step) ----
    {
      const u32* xrow = xs_pk + ((size_t)s*BAT + batch)*HID + lhi*8;
#pragma unroll
      for (int kk = 0; kk < 24; ++kk) {
        const uint4* p = (const uint4*)(xrow + kk*32);
        uint4 a = p[0], b = p[1];
        u32 w[8] = {a.x, a.y, a.z, a.w, b.x, b.y, b.z, b.w};
        bf16x8 bhi, blo;
        unpack8(w, bhi, blo);
        acc[(3*kk+0)&3] = __builtin_amdgcn_mfma_f32_16x16x32_bf16(ah[kk], bhi, acc[(3*kk+0)&3], 0, 0, 0);
        acc[(3*kk+1)&3] = __builtin_amdgcn_mfma_f32_16x16x32_bf16(al[kk], bhi, acc[(3*kk+1)&3], 0, 0, 0);
        acc[(3*kk+2)&3] = __builtin_amdgcn_mfma_f32_16x16x32_bf16(ah[kk], blo, acc[(3*kk+2)&3], 0, 0, 0);
      }
    }

    // ---- recurrent contribution ----
    if (s > 0) {
      if (tid < 64) {
        while (true) {
          int v = __hip_atomic_load(gflags + l, __ATOMIC_RELAXED, __HIP_MEMORY_SCOPE_AGENT);
          if (__all(v >= s)) break;
          __builtin_amdgcn_s_sleep(2);
        }
      }
      __syncthreads();                 // all waves wait for poll wave
      asm volatile("" ::: "memory");   // keep h loads below the barrier
      // plain cached loads: slice s-1 addresses were never read before in this
      // kernel -> no stale line possible; producer wrote through to MALL.
      const u32* hrow = hout + ((size_t)(s-1)*BAT + batch)*HID + lhi*8;
#pragma unroll
      for (int kk = 0; kk < 24; ++kk) {
        const uint4* p = (const uint4*)(hrow + kk*32);
        uint4 a = p[0], b = p[1];
        u32 w[8] = {a.x, a.y, a.z, a.w, b.x, b.y, b.z, b.w};
        bf16x8 bhi, blo;
        unpack8(w, bhi, blo);
        acc[(3*kk+0)&3] = __builtin_amdgcn_mfma_f32_16x16x32_bf16(ah[24+kk], bhi, acc[(3*kk+0)&3], 0, 0, 0);
        acc[(3*kk+1)&3] = __builtin_amdgcn_mfma_f32_16x16x32_bf16(al[24+kk], bhi, acc[(3*kk+1)&3], 0, 0, 0);
        acc[(3*kk+2)&3] = __builtin_amdgcn_mfma_f32_16x16x32_bf16(ah[24+kk], blo, acc[(3*kk+2)&3], 0, 0, 0);
      }
    }

    // ---- gates / state update ----
    float zi = acc[0][0]+acc[1][0]+acc[2][0]+acc[3][0] + bias[0];
    float zf = acc[0][1]+acc[1][1]+acc[2][1]+acc[3][1] + bias[1];
    float zg = acc[0][2]+acc[1][2]+acc[2][2]+acc[3][2] + bias[2];
    float zo = acc[0][3]+acc[1][3]+acc[2][3]+acc[3][3] + bias[3];
    float iv = sigm(zi), fv = sigm(zf), gv = tanh_fast(zg), ov = sigm(zo);
    float c  = fv*cstate + iv*gv;
    float hv = ov * tanh_fast(c);
    float m  = mrow[s];
    hv *= m; c *= m; cstate = c;

    // ---- publish h_s (MALL write-through store) ----
    u32 hw = packsplit(hv);
    __hip_atomic_store(hout + ((size_t)s*BAT + batch)*HID + col, hw,
                       __ATOMIC_RELAXED, __HIP_MEMORY_SCOPE_AGENT);
    if constexpr (WRITE_OUT) {
      __builtin_nontemporal_store(hv, out_f + (size_t)(batch*SEQ + s)*HID + col);
    }
    if (s == SEQ - 1) {
      hn[batch*HID + col] = hv;
      cn[batch*HID + col] = c;
    }

    // ---- ordering: store-ack (MALL visibility) then flag ----
    asm volatile("s_waitcnt vmcnt(0)" ::: "memory");
    __syncthreads();     // every wave has drained its stores
    if (tid == 0)
      __hip_atomic_store(gflags + wid, s + 1,
                         __ATOMIC_RELAXED, __HIP_MEMORY_SCOPE_AGENT);
  }
}

extern "C" void kernel_launch(void* const* d_in, const int* in_sizes, int n_in,
                              void* d_out, int out_size, void* d_ws, size_t ws_size,
                              hipStream_t stream) {
  const float* x    = (const float*)d_in[0];
  const float* mask = (const float*)d_in[1];
  const float* Wih  = (const float*)d_in[2];
  const float* Whh  = (const float*)d_in[3];
  const float* bih  = (const float*)d_in[4];
  const float* bhh  = (const float*)d_in[5];
  float* out = (float*)d_out;

  char* ws = (char*)d_ws;
  const size_t STREAM_B = (size_t)SEQ * BAT * HID * sizeof(u32);  // 100663296
  u32* xpk  = (u32*)(ws);                 // L0 input; later reused as L1 h-stream
  u32* opk  = (u32*)(ws + STREAM_B);      // L0 h-stream = L1 input
  int* flags = (int*)(ws + 2*STREAM_B);   // 2*NWG*4

  hipMemsetAsync(flags, 0, 2*NWG*sizeof(int), stream);
  pack_x<<<2048, 256, 0, stream>>>(x, xpk);

  float* hn = out + 25165824;            // [2][64][768]
  float* cn = out + 25165824 + 98304;

  // ---- layer 0 ----  (input xpk, h-stream -> opk)
  lstm_scan<0><<<dim3(NWG), dim3(TPB), 0, stream>>>(
      xpk, mask, Wih, Whh, bih, bhh,
      opk, /*out_f=*/nullptr, hn, cn, flags);

  // ---- layer 1 ----  (input opk, h-stream -> xpk region [dead], writes out)
  lstm_scan<1><<<dim3(NWG), dim3(TPB), 0, stream>>>(
      opk, mask,
      Wih + (size_t)FH*HID, Whh + (size_t)FH*HID, bih + FH, bhh + FH,
      xpk, /*out_f=*/out, hn + 49152, cn + 49152, flags + NWG);
}

// Round 8
// 11619.761 us; speedup vs baseline: 4.5284x; 1.6473x over previous
//
#include <hip/hip_runtime.h>
#include <hip/hip_bf16.h>

// LSTM: B=64, S=512, H=768, L=2. Persistent scan per layer.
// 12 waves/WG, wave-specialized:
//   waves 0-5: x-projection (W_ih), K split 2-way per tile, pipelined 1 step
//              ahead into a 4-deep LDS ring (latency fully hidden).
//   waves 6-11: h-projection (W_hh), K split 2-way per tile; odd waves
//              finalize gates/state and publish h.
// Per-wave weights: 24 split-bf16 fragments = 96 VGPRs -> register-resident,
// leaving ~90 regs for in-flight loads (the round-5 bottleneck).
// h exchange: MALL-bypass relaxed-agent stores + vmcnt ack + flag; consumers
// plain cached loads on write-once streams (round-5-proven protocol).

#define HID 768
#define FH  3072
#define SEQ 512
#define BAT 64
#define GB  16           // batches per group
#define WPG 64           // workgroups per group
#define CPW 12           // h-columns per workgroup (3 tiles x 4 cols)
#define NWG 256
#define TPB 768          // 12 waves

typedef __attribute__((ext_vector_type(8))) __bf16 bf16x8;
typedef __attribute__((ext_vector_type(4))) float f32x4;
typedef unsigned int u32;

__device__ __forceinline__ float sigm(float z) { return 1.f / (1.f + __expf(-z)); }
__device__ __forceinline__ float tanh_fast(float x) {
  float a = fabsf(x);
  float e = __expf(-2.f * a);
  float t = (1.f - e) / (1.f + e);
  return copysignf(t, x);
}
__device__ __forceinline__ unsigned short bfbits(__bf16 b) {
  union { __bf16 b; unsigned short s; } u; u.b = b; return u.s;
}
__device__ __forceinline__ __bf16 bits2bf(unsigned short s) {
  union { unsigned short s; __bf16 b; } u; u.s = s; return u.b;
}
__device__ __forceinline__ u32 packsplit(float v) {
  __bf16 h = (__bf16)v;
  __bf16 l = (__bf16)(v - (float)h);
  return ((u32)bfbits(h) << 16) | (u32)bfbits(l);
}
__device__ __forceinline__ void split8(const float* p, bf16x8& hi, bf16x8& lo) {
  const float4* q = (const float4*)p;
  float4 a = q[0], b = q[1];
  float v[8] = {a.x, a.y, a.z, a.w, b.x, b.y, b.z, b.w};
#pragma unroll
  for (int i = 0; i < 8; ++i) {
    __bf16 h = (__bf16)v[i];
    hi[i] = h;
    lo[i] = (__bf16)(v[i] - (float)h);
  }
}
__device__ __forceinline__ void unpack8(const u32 w[8], bf16x8& hi, bf16x8& lo) {
#pragma unroll
  for (int i = 0; i < 8; ++i) {
    hi[i] = bits2bf((unsigned short)(w[i] >> 16));
    lo[i] = bits2bf((unsigned short)(w[i] & 0xffffu));
  }
}

// K=384 projection slice: 12 chunks x 3 MFMAs, returns summed D fragment.
// FMT 0: fp32 source (split on the fly); FMT 1: packed hi|lo u32 pairs.
template<int FMT>
__device__ __forceinline__ f32x4 proj384(const float* xf, const u32* xp,
                                         size_t base,
                                         const bf16x8* ah, const bf16x8* al) {
  f32x4 acc[4];
#pragma unroll
  for (int r = 0; r < 4; ++r) acc[r] = f32x4{0.f, 0.f, 0.f, 0.f};
#pragma unroll
  for (int kk = 0; kk < 12; ++kk) {
    bf16x8 bhi, blo;
    if constexpr (FMT == 0) {
      split8(xf + base + kk*32, bhi, blo);
    } else {
      const uint4* p = (const uint4*)(xp + base + kk*32);
      uint4 A = p[0], B = p[1];
      u32 w[8] = {A.x, A.y, A.z, A.w, B.x, B.y, B.z, B.w};
      unpack8(w, bhi, blo);
    }
    acc[(3*kk+0)&3] = __builtin_amdgcn_mfma_f32_16x16x32_bf16(ah[kk], bhi, acc[(3*kk+0)&3], 0, 0, 0);
    acc[(3*kk+1)&3] = __builtin_amdgcn_mfma_f32_16x16x32_bf16(al[kk], bhi, acc[(3*kk+1)&3], 0, 0, 0);
    acc[(3*kk+2)&3] = __builtin_amdgcn_mfma_f32_16x16x32_bf16(ah[kk], blo, acc[(3*kk+2)&3], 0, 0, 0);
  }
  return acc[0] + acc[1] + acc[2] + acc[3];
}

template<int XFMT, int WRITE_OUT>
__global__ void __launch_bounds__(TPB, 3)
lstm_scan(const float* __restrict__ xf,   // XFMT==0: raw x [64][512][768] fp32
          const u32* __restrict__ xp,     // XFMT==1: packed pairs [512][64][768]
          const float* __restrict__ mask, // [64][512]
          const float* __restrict__ Wih,  // [3072][768] this layer
          const float* __restrict__ Whh,
          const float* __restrict__ bih,
          const float* __restrict__ bhh,
          u32* __restrict__ hstream,      // h stream [512][64][768] packed pairs
          float* __restrict__ out_f,      // WRITE_OUT: [64][512][768]
          float* __restrict__ hn,         // [64][768] this layer
          float* __restrict__ cn,
          int* __restrict__ flags)        // [NWG] this layer, zeroed
{
  __shared__ f32x4 xacc_l[4][3][64];      // x-proj results, 4-deep ring (12 KB)
  __shared__ f32x4 xpart_l[3][64];        // x K-half partial (3 KB)
  __shared__ f32x4 hpart_l[2][3][64];     // h K-half partial, dbuf (6 KB)

  const int wg  = blockIdx.x;
  const int grp = wg >> 6;
  const int wid = wg & 63;
  const int tid = threadIdx.x;
  const int wv  = tid >> 6;        // 0..11
  const int l   = tid & 63;
  const int l15 = l & 15;
  const int lhi = l >> 4;

  const bool isx  = (wv < 6);
  const int lane6 = isx ? wv : (wv - 6);
  const int tile  = lane6 >> 1;    // 0..2
  const int half  = lane6 & 1;     // K-half within the 768-K GEMM
  const int kofs  = half * 384;

  // ---- weights (split-bf16) -> registers: 12 chunks = 24 frags = 96 VGPRs.
  // A-fragment: M-row m = l15 = 4*c_loc + gate; k = kofs + kk*32 + lhi*8 + i
  const int colA = wid*CPW + tile*4 + (l15 >> 2);
  const int qA   = l15 & 3;
  const float* wrow = (isx ? Wih : Whh) + (size_t)(qA*HID + colA)*HID + kofs + lhi*8;
  bf16x8 ah[12], al[12];
#pragma unroll
  for (int kk = 0; kk < 12; ++kk) split8(wrow + kk*32, ah[kk], al[kk]);

  // ---- per-lane output ownership (D: col=l15 -> batch, elem j -> gate j of colO)
  const int batch = grp*GB + l15;
  const int colO  = wid*CPW + tile*4 + lhi;
  float bias4[4] = {0.f, 0.f, 0.f, 0.f};
  if (!isx && half == 1) {
#pragma unroll
    for (int j = 0; j < 4; ++j) bias4[j] = bih[j*HID + colO] + bhh[j*HID + colO];
  }
  const float* mrow = mask + batch*SEQ;
  int* gflags = flags + grp*WPG;

  const int kb = kofs + lhi*8;     // per-lane K element offset

  float cstate = 0.f;

  // ---- prologue: produce xacc(0) into ring slot 0 ----
  {
    f32x4 px{0.f, 0.f, 0.f, 0.f};
    if (isx) {
      size_t base = (XFMT == 0) ? ((size_t)batch*SEQ)*HID + kb
                                : ((size_t)batch)*HID + kb;
      px = proj384<XFMT>(xf, xp, base, ah, al);
      if (half == 0) xpart_l[tile][l] = px;
    }
    __syncthreads();
    if (isx && half == 1) {
      f32x4 t = xpart_l[tile][l];
      xacc_l[0][tile][l] = px + t;
    }
    __syncthreads();
  }

#pragma unroll 1
  for (int s = 0; s < SEQ; ++s) {
    // ---- phase0: x-waves compute step s+1; poller waits flag(s) ----
    f32x4 xa{0.f, 0.f, 0.f, 0.f};
    if (isx && s + 1 < SEQ) {
      size_t base = (XFMT == 0) ? ((size_t)batch*SEQ + (s+1))*HID + kb
                                : ((size_t)(s+1)*BAT + batch)*HID + kb;
      xa = proj384<XFMT>(xf, xp, base, ah, al);
      if (half == 0) xpart_l[tile][l] = xa;
    }
    if (!isx && lane6 == 0 && s > 0) {     // wave 6 polls for the whole WG
      while (true) {
        int v = __hip_atomic_load(gflags + l, __ATOMIC_RELAXED, __HIP_MEMORY_SCOPE_AGENT);
        if (__all(v >= s)) break;
        __builtin_amdgcn_s_sleep(1);
      }
    }
    __syncthreads();   // b1: flag released; xpart(s+1) visible

    // ---- phase1: h-waves load h(s-1) + MFMA; x-b folds xpart into ring ----
    f32x4 ha{0.f, 0.f, 0.f, 0.f};
    if (!isx && s > 0) {
      size_t base = ((size_t)(s-1)*BAT + batch)*HID + kb;
      ha = proj384<1>(nullptr, hstream, base, ah, al);
      if (half == 0) hpart_l[s & 1][tile][l] = ha;
    }
    if (isx && half == 1 && s + 1 < SEQ) {
      f32x4 t = xpart_l[tile][l];
      xacc_l[(s+1) & 3][tile][l] = xa + t;
    }
    __syncthreads();   // b2: hpart + xacc ready

    // ---- phase2: finalize (odd h-waves own the output) ----
    if (!isx && half == 1) {
      f32x4 z = xacc_l[s & 3][tile][l];
      if (s > 0) { f32x4 hp = hpart_l[s & 1][tile][l]; z = z + ha + hp; }
      float zi = z[0] + bias4[0], zf = z[1] + bias4[1];
      float zg = z[2] + bias4[2], zo = z[3] + bias4[3];
      float iv = sigm(zi), fv = sigm(zf), gv = tanh_fast(zg), ov = sigm(zo);
      float c  = fv*cstate + iv*gv;
      float hv = ov * tanh_fast(c);
      float m  = mrow[s];
      hv *= m; c *= m; cstate = c;

      u32 hw = packsplit(hv);
      __hip_atomic_store(hstream + ((size_t)s*BAT + batch)*HID + colO, hw,
                         __ATOMIC_RELAXED, __HIP_MEMORY_SCOPE_AGENT);
      if constexpr (WRITE_OUT) {
        __builtin_nontemporal_store(hv, out_f + ((size_t)batch*SEQ + s)*HID + colO);
      }
      if (s == SEQ - 1) {
        hn[batch*HID + colO] = hv;
        cn[batch*HID + colO] = c;
      }
      asm volatile("s_waitcnt vmcnt(0)" ::: "memory");  // h at MALL before flag
    }
    __syncthreads();   // b3: all finalizers drained
    if (tid == 0)
      __hip_atomic_store(gflags + wid, s + 1,
                         __ATOMIC_RELAXED, __HIP_MEMORY_SCOPE_AGENT);
  }
}

extern "C" void kernel_launch(void* const* d_in, const int* in_sizes, int n_in,
                              void* d_out, int out_size, void* d_ws, size_t ws_size,
                              hipStream_t stream) {
  const float* x    = (const float*)d_in[0];
  const float* mask = (const float*)d_in[1];
  const float* Wih  = (const float*)d_in[2];
  const float* Whh  = (const float*)d_in[3];
  const float* bih  = (const float*)d_in[4];
  const float* bhh  = (const float*)d_in[5];
  float* out = (float*)d_out;

  char* ws = (char*)d_ws;
  const size_t STREAM_B = (size_t)SEQ * BAT * HID * sizeof(u32);  // 100663296
  u32* opk   = (u32*)(ws);                // L0 h-stream = L1 input
  u32* hpk   = (u32*)(ws + STREAM_B);     // L1 h-stream
  int* flags = (int*)(ws + 2*STREAM_B);   // 2*NWG*4

  (void)hipMemsetAsync(flags, 0, 2*NWG*sizeof(int), stream);

  float* hn = out + 25165824;             // [2][64][768]
  float* cn = out + 25165824 + 98304;

  // ---- layer 0: raw fp32 x input, h-stream -> opk ----
  lstm_scan<0, 0><<<dim3(NWG), dim3(TPB), 0, stream>>>(
      x, nullptr, mask, Wih, Whh, bih, bhh,
      opk, nullptr, hn, cn, flags);

  // ---- layer 1: packed opk input, h-stream -> hpk, writes out ----
  lstm_scan<1, 1><<<dim3(NWG), dim3(TPB), 0, stream>>>(
      nullptr, opk, mask,
      Wih + (size_t)FH*HID, Whh + (size_t)FH*HID, bih + FH, bhh + FH,
      hpk, out, hn + 49152, cn + 49152, flags + NWG);
}